// Round 1
// baseline (10890.514 us; speedup 1.0000x reference)
//
#include <hip/hip_runtime.h>
#include <cmath>

#define S_TOT 4096
#define CIN   256
#define HID   512   // HEADS * DIM_HEAD
#define NHEAD 8
#define DIMH  64

// ---------------------------------------------------------------------------
// Generic tiled fp32 GEMM: C[M][N] = A[M][K] * B[K][N] (+ bias[M])
// A row-major, B row-major, C row-major. Batch via blockIdx.z with strides.
// BM=BN=64, BK=16, 256 threads, 4x4 micro-tile per thread.
// ---------------------------------------------------------------------------
__global__ __launch_bounds__(256)
void gemm_f32_kernel(const float* __restrict__ A, const float* __restrict__ B,
                     float* __restrict__ C, const float* __restrict__ bias,
                     int M, int N, int K,
                     long strideA, long strideB, long strideC) {
    __shared__ float As[64][17];
    __shared__ float Bs[16][65];

    const int bz = blockIdx.z;
    A += (long)bz * strideA;
    B += (long)bz * strideB;
    C += (long)bz * strideC;

    const int bm = blockIdx.y * 64;
    const int bn = blockIdx.x * 64;
    const int tid = threadIdx.x;           // 0..255
    const int tx = tid & 15;                // n-dir
    const int ty = tid >> 4;                // m-dir

    float acc[4][4] = {};

    for (int k0 = 0; k0 < K; k0 += 16) {
        // load A tile 64x16 (4 elems/thread)
        #pragma unroll
        for (int it = 0; it < 4; ++it) {
            int idx = tid + it * 256;
            int r = idx >> 4, c = idx & 15;
            As[r][c] = A[(long)(bm + r) * K + k0 + c];
        }
        // load B tile 16x64 (4 elems/thread)
        #pragma unroll
        for (int it = 0; it < 4; ++it) {
            int idx = tid + it * 256;
            int r = idx >> 6, c = idx & 63;
            Bs[r][c] = B[(long)(k0 + r) * N + bn + c];
        }
        __syncthreads();

        #pragma unroll
        for (int kk = 0; kk < 16; ++kk) {
            float a[4], b[4];
            #pragma unroll
            for (int m = 0; m < 4; ++m) a[m] = As[ty * 4 + m][kk];
            #pragma unroll
            for (int n = 0; n < 4; ++n) b[n] = Bs[kk][tx * 4 + n];
            #pragma unroll
            for (int m = 0; m < 4; ++m)
                #pragma unroll
                for (int n = 0; n < 4; ++n)
                    acc[m][n] = fmaf(a[m], b[n], acc[m][n]);
        }
        __syncthreads();
    }

    #pragma unroll
    for (int m = 0; m < 4; ++m) {
        const int row = bm + ty * 4 + m;
        const float bv = bias ? bias[row] : 0.0f;
        #pragma unroll
        for (int n = 0; n < 4; ++n)
            C[(long)row * N + bn + tx * 4 + n] = acc[m][n] + bv;
    }
}

// ---------------------------------------------------------------------------
// Attention: one block (256 threads) per query row i of one (b,h).
// qkv layout: [b][1536][4096] where rows 0..511 = q (h*64+d), 512..1023 = k,
// 1024..1535 = v. Stored d-major: q[d][s].
// Output attnout[b][h*64+d][s=i] = sum_j softmax_j(q·k/8) * v[d][j]
// ---------------------------------------------------------------------------
__global__ __launch_bounds__(256)
void attn_row_kernel(const float* __restrict__ qkv, float* __restrict__ out) {
    const int i = blockIdx.x;   // query position 0..4095
    const int h = blockIdx.y;   // head
    const int b = blockIdx.z;   // batch

    const float* q = qkv + ((long)b * 1536 + h * 64) * S_TOT;
    const float* k = q + (long)HID * S_TOT;
    const float* v = q + (long)(2 * HID) * S_TOT;

    __shared__ float qs[64];
    __shared__ float p[S_TOT];
    __shared__ float red[4];
    __shared__ float reds[256];

    const int t = threadIdx.x;

    if (t < 64) qs[t] = q[(long)t * S_TOT + i] * 0.125f;  // 1/sqrt(64)
    __syncthreads();

    // --- QK^T row: each thread handles 16 j's (j = jj*256 + t) ---
    float sims[16];
    float lmax = -1e30f;
    #pragma unroll
    for (int jj = 0; jj < 16; ++jj) {
        const int j = jj * 256 + t;
        float s = 0.0f;
        #pragma unroll
        for (int d = 0; d < 64; ++d)
            s = fmaf(qs[d], k[(long)d * S_TOT + j], s);
        sims[jj] = s;
        lmax = fmaxf(lmax, s);
    }

    // block max reduce (wave64 butterfly + cross-wave)
    #pragma unroll
    for (int off = 32; off; off >>= 1)
        lmax = fmaxf(lmax, __shfl_xor(lmax, off, 64));
    if ((t & 63) == 0) red[t >> 6] = lmax;
    __syncthreads();
    const float gmax = fmaxf(fmaxf(red[0], red[1]), fmaxf(red[2], red[3]));
    __syncthreads();

    // --- exp + sum ---
    float lsum = 0.0f;
    #pragma unroll
    for (int jj = 0; jj < 16; ++jj) {
        const float e = __expf(sims[jj] - gmax);
        p[jj * 256 + t] = e;
        lsum += e;
    }
    #pragma unroll
    for (int off = 32; off; off >>= 1)
        lsum += __shfl_xor(lsum, off, 64);
    if ((t & 63) == 0) red[t >> 6] = lsum;
    __syncthreads();
    const float inv = 1.0f / (red[0] + red[1] + red[2] + red[3]);

    // --- PV: 4 groups of 64 threads; group g covers j in [g*1024,(g+1)*1024),
    //     thread handles one d = t&63, streams its own v row segment ---
    const int d = t & 63, g = t >> 6;
    const float* vrow = v + (long)d * S_TOT + g * 1024;
    const float* prow = p + g * 1024;
    float acc = 0.0f;
    #pragma unroll 4
    for (int j = 0; j < 1024; ++j)
        acc = fmaf(prow[j], vrow[j], acc);

    reds[t] = acc;
    __syncthreads();
    if (t < 64) {
        const float o = (reds[t] + reds[t + 64] + reds[t + 128] + reds[t + 192]) * inv;
        out[((long)b * HID + h * 64 + t) * S_TOT + i] = o;
    }
}

// ---------------------------------------------------------------------------
extern "C" void kernel_launch(void* const* d_in, const int* in_sizes, int n_in,
                              void* d_out, int out_size, void* d_ws, size_t ws_size,
                              hipStream_t stream) {
    const float* x     = (const float*)d_in[0];   // [2,256,64,64]
    const float* w_qkv = (const float*)d_in[1];   // [1536,256]
    const float* w_out = (const float*)d_in[2];   // [256,512]
    const float* b_out = (const float*)d_in[3];   // [256]
    float* out = (float*)d_out;                    // [2,256,64,64]

    float* qkv_ws  = (float*)d_ws;                           // 2*1536*4096 floats
    float* attn_ws = qkv_ws + (long)2 * 1536 * S_TOT;        // 2*512*4096 floats

    // 1) QKV projection: per batch, qkv[o][s] = sum_c w_qkv[o][c] * x[c][s]
    {
        dim3 grid(S_TOT / 64, (3 * HID) / 64, 2);
        gemm_f32_kernel<<<grid, 256, 0, stream>>>(
            w_qkv, x, qkv_ws, nullptr,
            3 * HID, S_TOT, CIN,
            0L, (long)CIN * S_TOT, (long)3 * HID * S_TOT);
    }

    // 2) attention per (row, head, batch)
    {
        dim3 grid(S_TOT, NHEAD, 2);
        attn_row_kernel<<<grid, 256, 0, stream>>>(qkv_ws, attn_ws);
    }

    // 3) output projection + bias: out[o][s] = sum_c2 w_out[o][c2]*attn[c2][s] + b_out[o]
    {
        dim3 grid(S_TOT / 64, CIN / 64, 2);
        gemm_f32_kernel<<<grid, 256, 0, stream>>>(
            w_out, attn_ws, out, b_out,
            CIN, S_TOT, HID,
            0L, (long)HID * S_TOT, (long)CIN * S_TOT);
    }
}

// Round 2
// 390.856 us; speedup vs baseline: 27.8632x; 27.8632x over previous
//
#include <hip/hip_runtime.h>
#include <cmath>

#define S_TOT 4096
#define CIN   256
#define HID   512
#define NHEAD 8
#define DIMH  64

typedef __attribute__((ext_vector_type(8))) short bf16x8;
typedef __attribute__((ext_vector_type(4))) float f32x4;
typedef __attribute__((address_space(1))) const void gv_t;
typedef __attribute__((address_space(3))) void lv_t;

__device__ __forceinline__ ushort f2bf(float f) {
    union { float f; unsigned u; } v; v.f = f;
    unsigned r = (v.u + 0x7FFFu + ((v.u >> 16) & 1u)) >> 16;
    return (ushort)r;
}

// ---------------------------------------------------------------------------
// QKV projection, fp32 math, bf16 epilogue into attention-friendly layouts:
//   q,k: [b*8+h][s][d]   (rows s, d contiguous -> A/B fragment 16B loads)
//   v:   [b*8+h][d][s]   (rows d, s contiguous -> PV B-operand 16B loads)
// ---------------------------------------------------------------------------
__global__ __launch_bounds__(256)
void gemm_qkv_kernel(const float* __restrict__ A, const float* __restrict__ B,
                     ushort* __restrict__ qws, ushort* __restrict__ kws,
                     ushort* __restrict__ vws) {
    __shared__ float As[64][17];
    __shared__ float Bs[16][65];
    const int bz = blockIdx.z;
    B += (long)bz * CIN * S_TOT;
    const int bm = blockIdx.y * 64;   // o (channel)
    const int bn = blockIdx.x * 64;   // s (spatial)
    const int tid = threadIdx.x;
    const int tx = tid & 15, ty = tid >> 4;

    float acc[4][4] = {};
    for (int k0 = 0; k0 < CIN; k0 += 16) {
        #pragma unroll
        for (int it = 0; it < 4; ++it) {
            int idx = tid + it * 256;
            int r = idx >> 4, c = idx & 15;
            As[r][c] = A[(long)(bm + r) * CIN + k0 + c];
        }
        #pragma unroll
        for (int it = 0; it < 4; ++it) {
            int idx = tid + it * 256;
            int r = idx >> 6, c = idx & 63;
            Bs[r][c] = B[(long)(k0 + r) * S_TOT + bn + c];
        }
        __syncthreads();
        #pragma unroll
        for (int kk = 0; kk < 16; ++kk) {
            float a[4], bb[4];
            #pragma unroll
            for (int m = 0; m < 4; ++m) a[m] = As[ty * 4 + m][kk];
            #pragma unroll
            for (int n = 0; n < 4; ++n) bb[n] = Bs[kk][tx * 4 + n];
            #pragma unroll
            for (int m = 0; m < 4; ++m)
                #pragma unroll
                for (int n = 0; n < 4; ++n)
                    acc[m][n] = fmaf(a[m], bb[n], acc[m][n]);
        }
        __syncthreads();
    }

    // block-uniform: which (q/k/v), head; d = ty*4+m, s = bn+tx*4+n
    const int which = bm >> 9;
    const int h = (bm >> 6) & 7;
    const int bh = bz * NHEAD + h;
    if (which < 2) {
        ushort* dst = (which == 0) ? qws : kws;
        #pragma unroll
        for (int n = 0; n < 4; ++n) {
            const long s = bn + tx * 4 + n;
            ushort4 pk;
            pk.x = f2bf(acc[0][n]); pk.y = f2bf(acc[1][n]);
            pk.z = f2bf(acc[2][n]); pk.w = f2bf(acc[3][n]);
            *(ushort4*)&dst[((long)bh * S_TOT + s) * DIMH + ty * 4] = pk;
        }
    } else {
        #pragma unroll
        for (int m = 0; m < 4; ++m) {
            const int d = ty * 4 + m;
            ushort4 pk;
            pk.x = f2bf(acc[m][0]); pk.y = f2bf(acc[m][1]);
            pk.z = f2bf(acc[m][2]); pk.w = f2bf(acc[m][3]);
            *(ushort4*)&vws[((long)bh * DIMH + d) * S_TOT + bn + tx * 4] = pk;
        }
    }
}

// ---------------------------------------------------------------------------
// Flash attention, bf16 MFMA 16x16x32. Block = 4 waves = 64 query rows.
// K/V tiles (64 keys) staged via global_load_lds into XOR-swizzled LDS
// (slot16B ^= row&7). Online softmax per lane (q = (lane>>4)*4+reg matches
// the C/D layout). P goes through a per-wave swizzled LDS tile to become the
// PV A-operand. Output: fp32 [b][s][hd] (coalesced).
// ---------------------------------------------------------------------------
__global__ __launch_bounds__(256)
void attn_mfma_kernel(const ushort* __restrict__ qg, const ushort* __restrict__ kg,
                      const ushort* __restrict__ vg, float* __restrict__ aout) {
    __shared__ __attribute__((aligned(16))) ushort kbuf[64 * 64];  // [key][d] swz
    __shared__ __attribute__((aligned(16))) ushort vbuf[64 * 64];  // [d][key] swz
    __shared__ __attribute__((aligned(16))) ushort pbuf[4][16 * 64]; // per-wave [q][key] swz

    const int t = threadIdx.x;
    const int lane = t & 63, wid = t >> 6;
    const int l15 = lane & 15, g = lane >> 4;
    const int h = blockIdx.y, b = blockIdx.z;
    const int bh = b * NHEAD + h;
    const int qrow0 = blockIdx.x * 64 + wid * 16;

    // Q A-fragments: row=l15, k(d) = g*8+j (frag0: d 0..31, frag1: d 32..63)
    const ushort* qp = qg + ((long)bh * S_TOT + qrow0 + l15) * DIMH + g * 8;
    const bf16x8 qf0 = *(const bf16x8*)qp;
    const bf16x8 qf1 = *(const bf16x8*)(qp + 32);

    f32x4 oacc[4];
    float mrun[4], lrun[4];
    #pragma unroll
    for (int r = 0; r < 4; ++r) { mrun[r] = -1e30f; lrun[r] = 0.f; }
    #pragma unroll
    for (int f = 0; f < 4; ++f) oacc[f] = (f32x4){0.f, 0.f, 0.f, 0.f};

    const long kg_base = (long)bh * S_TOT * DIMH;   // ushort idx
    const long vg_base = (long)bh * DIMH * S_TOT;

    const int sl = lane & 7, sr = lane >> 3;
    const int swz = sl ^ sr;                         // pre-swizzled source slot
    char* kdst = (char*)kbuf + wid * 1024;
    char* vdst = (char*)vbuf + wid * 1024;
    char* pbase = (char*)(&pbuf[wid][0]);

    for (int kt0 = 0; kt0 < S_TOT / 64; ++kt0) {
        const long key0 = (long)kt0 * 64;
        __syncthreads();   // prior tile fully consumed before overwrite
        // stage K tile: wave handles chunks wid, wid+4 (1 KB each)
        #pragma unroll
        for (int c = 0; c < 2; ++c) {
            const int row = (wid + c * 4) * 8 + sr;  // key-in-tile
            const char* src = (const char*)(kg + kg_base + (key0 + row) * DIMH) + swz * 16;
            __builtin_amdgcn_global_load_lds((gv_t*)src, (lv_t*)(kdst + c * 4096), 16, 0, 0);
        }
        // stage V tile ([d][key] rows)
        #pragma unroll
        for (int c = 0; c < 2; ++c) {
            const int d = (wid + c * 4) * 8 + sr;
            const char* src = (const char*)(vg + vg_base + (long)d * S_TOT + key0) + swz * 16;
            __builtin_amdgcn_global_load_lds((gv_t*)src, (lv_t*)(vdst + c * 4096), 16, 0, 0);
        }
        asm volatile("s_waitcnt vmcnt(0)" ::: "memory");
        __syncthreads();

        // --- S = (Q K^T) * scale ---
        f32x4 sacc[4];
        #pragma unroll
        for (int kt = 0; kt < 4; ++kt) {
            sacc[kt] = (f32x4){0.f, 0.f, 0.f, 0.f};
            const int krow = kt * 16 + l15;
            const int ks = krow & 7;
            const bf16x8 kf0 = *(const bf16x8*)((const char*)kbuf + krow * 128 + ((g) ^ ks) * 16);
            sacc[kt] = __builtin_amdgcn_mfma_f32_16x16x32_bf16(qf0, kf0, sacc[kt], 0, 0, 0);
            const bf16x8 kf1 = *(const bf16x8*)((const char*)kbuf + krow * 128 + ((4 + g) ^ ks) * 16);
            sacc[kt] = __builtin_amdgcn_mfma_f32_16x16x32_bf16(qf1, kf1, sacc[kt], 0, 0, 0);
            #pragma unroll
            for (int r = 0; r < 4; ++r) sacc[kt][r] *= 0.125f;
        }

        // --- online softmax (q = g*4 + r) ---
        float mx[4];
        #pragma unroll
        for (int r = 0; r < 4; ++r)
            mx[r] = fmaxf(fmaxf(sacc[0][r], sacc[1][r]), fmaxf(sacc[2][r], sacc[3][r]));
        #pragma unroll
        for (int off = 1; off < 16; off <<= 1) {
            #pragma unroll
            for (int r = 0; r < 4; ++r)
                mx[r] = fmaxf(mx[r], __shfl_xor(mx[r], off, 64));
        }
        float al[4];
        #pragma unroll
        for (int r = 0; r < 4; ++r) {
            const float mn = fmaxf(mrun[r], mx[r]);
            al[r] = __expf(mrun[r] - mn);
            mrun[r] = mn;
        }
        float ps[4] = {0.f, 0.f, 0.f, 0.f};
        #pragma unroll
        for (int kt = 0; kt < 4; ++kt) {
            #pragma unroll
            for (int r = 0; r < 4; ++r) {
                const float p = __expf(sacc[kt][r] - mrun[r]);
                ps[r] += p;
                const int q = g * 4 + r;
                // P[q][key], key = kt*16+l15, 16B-slot swizzled by q&7
                *(ushort*)(pbase + q * 128 + (((kt * 2 + (l15 >> 3)) ^ (q & 7)) << 4)
                           + (l15 & 7) * 2) = f2bf(p);
            }
        }
        #pragma unroll
        for (int off = 1; off < 16; off <<= 1) {
            #pragma unroll
            for (int r = 0; r < 4; ++r)
                ps[r] += __shfl_xor(ps[r], off, 64);
        }
        #pragma unroll
        for (int r = 0; r < 4; ++r)
            lrun[r] = lrun[r] * al[r] + ps[r];
        #pragma unroll
        for (int f = 0; f < 4; ++f)
            #pragma unroll
            for (int r = 0; r < 4; ++r)
                oacc[f][r] *= al[r];

        // --- O += P V ---
        #pragma unroll
        for (int ks = 0; ks < 2; ++ks) {
            const bf16x8 pf = *(const bf16x8*)(pbase + l15 * 128
                                + (((ks * 4 + g) ^ (l15 & 7)) << 4));
            #pragma unroll
            for (int f = 0; f < 4; ++f) {
                const int vrow = f * 16 + l15;
                const bf16x8 vf = *(const bf16x8*)((const char*)vbuf + vrow * 128
                                    + (((ks * 4 + g) ^ (vrow & 7)) << 4));
                oacc[f] = __builtin_amdgcn_mfma_f32_16x16x32_bf16(pf, vf, oacc[f], 0, 0, 0);
            }
        }
    }

    // epilogue: out[b][s][hd] fp32, coalesced (16 lanes x 4B contiguous)
    float inv[4];
    #pragma unroll
    for (int r = 0; r < 4; ++r) inv[r] = 1.0f / lrun[r];
    #pragma unroll
    for (int f = 0; f < 4; ++f)
        #pragma unroll
        for (int r = 0; r < 4; ++r) {
            const long srow = (long)b * S_TOT + qrow0 + g * 4 + r;
            aout[srow * HID + h * 64 + f * 16 + l15] = oacc[f][r] * inv[r];
        }
}

// ---------------------------------------------------------------------------
// Output projection: C[o][s] = sum_k w_out[o][k] * attn[s][k] + bias[o]
// (attn buffer is [b][s][512] fp32; loads transposed through LDS)
// ---------------------------------------------------------------------------
__global__ __launch_bounds__(256)
void gemm_out_kernel(const float* __restrict__ A, const float* __restrict__ Bt,
                     float* __restrict__ C, const float* __restrict__ bias) {
    __shared__ float As[64][17];
    __shared__ float Bs[16][65];
    const int bz = blockIdx.z;
    Bt += (long)bz * S_TOT * HID;
    C  += (long)bz * CIN * S_TOT;
    const int bm = blockIdx.y * 64;
    const int bn = blockIdx.x * 64;
    const int tid = threadIdx.x;
    const int tx = tid & 15, ty = tid >> 4;

    float acc[4][4] = {};
    for (int k0 = 0; k0 < HID; k0 += 16) {
        #pragma unroll
        for (int it = 0; it < 4; ++it) {
            int idx = tid + it * 256;
            int r = idx >> 4, c = idx & 15;
            As[r][c] = A[(long)(bm + r) * HID + k0 + c];
        }
        {
            const int s_l = tid >> 2, k_l = (tid & 3) * 4;
            const float4 bv = *(const float4*)&Bt[(long)(bn + s_l) * HID + k0 + k_l];
            Bs[k_l + 0][s_l] = bv.x; Bs[k_l + 1][s_l] = bv.y;
            Bs[k_l + 2][s_l] = bv.z; Bs[k_l + 3][s_l] = bv.w;
        }
        __syncthreads();
        #pragma unroll
        for (int kk = 0; kk < 16; ++kk) {
            float a[4], bb[4];
            #pragma unroll
            for (int m = 0; m < 4; ++m) a[m] = As[ty * 4 + m][kk];
            #pragma unroll
            for (int n = 0; n < 4; ++n) bb[n] = Bs[kk][tx * 4 + n];
            #pragma unroll
            for (int m = 0; m < 4; ++m)
                #pragma unroll
                for (int n = 0; n < 4; ++n)
                    acc[m][n] = fmaf(a[m], bb[n], acc[m][n]);
        }
        __syncthreads();
    }
    #pragma unroll
    for (int m = 0; m < 4; ++m) {
        const int row = bm + ty * 4 + m;
        const float bv = bias[row];
        #pragma unroll
        for (int n = 0; n < 4; ++n)
            C[(long)row * S_TOT + bn + tx * 4 + n] = acc[m][n] + bv;
    }
}

// ---------------------------------------------------------------------------
extern "C" void kernel_launch(void* const* d_in, const int* in_sizes, int n_in,
                              void* d_out, int out_size, void* d_ws, size_t ws_size,
                              hipStream_t stream) {
    const float* x     = (const float*)d_in[0];   // [2,256,64,64]
    const float* w_qkv = (const float*)d_in[1];   // [1536,256]
    const float* w_out = (const float*)d_in[2];   // [256,512]
    const float* b_out = (const float*)d_in[3];   // [256]
    float* out = (float*)d_out;                    // [2,256,64,64]

    ushort* qws = (ushort*)d_ws;                         // 16*4096*64 bf16
    const long perqkv = (long)2 * NHEAD * S_TOT * DIMH;  // 4,194,304
    ushort* kws = qws + perqkv;
    ushort* vws = kws + perqkv;
    float*  aws = (float*)(vws + perqkv);                // [2][4096][512] fp32

    {   // 1) QKV projection (fp32 math, bf16 layout-aware epilogue)
        dim3 grid(S_TOT / 64, (3 * HID) / 64, 2);
        gemm_qkv_kernel<<<grid, 256, 0, stream>>>(w_qkv, x, qws, kws, vws);
    }
    {   // 2) flash attention, bf16 MFMA
        dim3 grid(S_TOT / 64, NHEAD, 2);
        attn_mfma_kernel<<<grid, 256, 0, stream>>>(qws, kws, vws, aws);
    }
    {   // 3) output projection + bias (fp32)
        dim3 grid(S_TOT / 64, CIN / 64, 2);
        gemm_out_kernel<<<grid, 256, 0, stream>>>(w_out, aws, out, b_out);
    }
}

// Round 3
// 261.376 us; speedup vs baseline: 41.6661x; 1.4954x over previous
//
#include <hip/hip_runtime.h>
#include <cmath>

#define S_TOT 4096
#define CIN   256
#define HID   512
#define NHEAD 8
#define DIMH  64

typedef __attribute__((ext_vector_type(8))) short bf16x8;
typedef __attribute__((ext_vector_type(4))) float f32x4;
typedef __attribute__((address_space(1))) const void gv_t;
typedef __attribute__((address_space(3))) void lv_t;

__device__ __forceinline__ ushort f2bf(float f) {
    union { float f; unsigned u; } v; v.f = f;
    unsigned r = (v.u + 0x7FFFu + ((v.u >> 16) & 1u)) >> 16;
    return (ushort)r;
}

// ---------------------------------------------------------------------------
// Elementwise fp32 -> bf16 cast (vectorized), n % 4 == 0
// ---------------------------------------------------------------------------
__global__ __launch_bounds__(256)
void cast_f32_bf16(const float* __restrict__ in, ushort* __restrict__ out, long n) {
    long i = ((long)blockIdx.x * 256 + threadIdx.x) * 4;
    if (i < n) {
        float4 v = *(const float4*)&in[i];
        ushort4 p;
        p.x = f2bf(v.x); p.y = f2bf(v.y); p.z = f2bf(v.z); p.w = f2bf(v.w);
        *(ushort4*)&out[i] = p;
    }
}

// ---------------------------------------------------------------------------
// Transpose-cast: x [b][256][4096] fp32 -> xt [b][4096][256] bf16
// ---------------------------------------------------------------------------
__global__ __launch_bounds__(256)
void transpose_cast_x(const float* __restrict__ x, ushort* __restrict__ xt) {
    __shared__ float tb[64][65];
    const int t = threadIdx.x;
    const int s0 = blockIdx.x * 64, c0 = blockIdx.y * 64;
    const long xb = (long)blockIdx.z * CIN * S_TOT;
    #pragma unroll
    for (int i = 0; i < 16; ++i) {
        int idx = t + i * 256;
        int c = idx >> 6, s = idx & 63;
        tb[c][s] = x[xb + (long)(c0 + c) * S_TOT + s0 + s];
    }
    __syncthreads();
    const long ob = (long)blockIdx.z * S_TOT * CIN;
    const int s = t >> 2, cq = (t & 3) * 16;
    #pragma unroll
    for (int j = 0; j < 4; ++j) {
        ushort4 pk;
        pk.x = f2bf(tb[cq + j * 4 + 0][s]);
        pk.y = f2bf(tb[cq + j * 4 + 1][s]);
        pk.z = f2bf(tb[cq + j * 4 + 2][s]);
        pk.w = f2bf(tb[cq + j * 4 + 3][s]);
        *(ushort4*)&xt[ob + (long)(s0 + s) * CIN + c0 + cq + j * 4] = pk;
    }
}

// ---------------------------------------------------------------------------
// bf16 MFMA GEMM: D[ar][br] = sum_k A[ar][k] * B[br][k]   (both K-contiguous)
// BM=BN=128, BK=64, 4 waves (each owns 64x64 = 4x4 frags of 16x16x32).
// Staging via global_load_lds w/ pre-swizzled source (slot ^= row&7).
// MODE 0: A=xt (s rows), B=w_qkv[0:1024] (o rows) -> q/k [bh][s][64] bf16
// MODE 1: A=w_qkv[1024:1536] (o rows), B=xt (s rows) -> v [bh][d][s] bf16
// MODE 2: A=w_out (o rows), B=attn-bf16 (s rows) -> out [b][o][s] fp32 + bias
// ---------------------------------------------------------------------------
template<int MODE>
__global__ __launch_bounds__(256)
void gemm_mfma_kernel(const ushort* __restrict__ Ag, const ushort* __restrict__ Bg,
                      void* __restrict__ outp, const float* __restrict__ bias,
                      int Kdim, long strideA, long strideB) {
    __shared__ __attribute__((aligned(16))) ushort Abuf[128 * 64];
    __shared__ __attribute__((aligned(16))) ushort Bbuf[128 * 64];
    const int t = threadIdx.x, lane = t & 63;
    const int l15 = lane & 15, g = lane >> 4;
    const int wid = t >> 6, wr = wid >> 1, wc = wid & 1;
    const int bz = blockIdx.z;
    const int am0 = blockIdx.y * 128, bn0 = blockIdx.x * 128;
    Ag += (long)bz * strideA;
    Bg += (long)bz * strideB;

    f32x4 acc[4][4];
    #pragma unroll
    for (int i = 0; i < 4; ++i)
        #pragma unroll
        for (int j = 0; j < 4; ++j)
            acc[i][j] = (f32x4){0.f, 0.f, 0.f, 0.f};

    for (int k0 = 0; k0 < Kdim; k0 += 64) {
        __syncthreads();
        #pragma unroll
        for (int i = 0; i < 4; ++i) {
            const int chunk = t + i * 256;            // 16B chunk id, 0..1023
            const int row = chunk >> 3, sl = chunk & 7;
            const ushort* srcA = Ag + (long)(am0 + row) * Kdim + k0 + ((sl ^ (row & 7)) << 3);
            __builtin_amdgcn_global_load_lds((gv_t*)srcA,
                (lv_t*)((char*)Abuf + (i * 256 + (t & ~63)) * 16), 16, 0, 0);
            const ushort* srcB = Bg + (long)(bn0 + row) * Kdim + k0 + ((sl ^ (row & 7)) << 3);
            __builtin_amdgcn_global_load_lds((gv_t*)srcB,
                (lv_t*)((char*)Bbuf + (i * 256 + (t & ~63)) * 16), 16, 0, 0);
        }
        asm volatile("s_waitcnt vmcnt(0)" ::: "memory");
        __syncthreads();

        bf16x8 bfr[4][2];
        #pragma unroll
        for (int fn = 0; fn < 4; ++fn) {
            const int row = wc * 64 + fn * 16 + l15;
            #pragma unroll
            for (int hf = 0; hf < 2; ++hf)
                bfr[fn][hf] = *(const bf16x8*)((const char*)Bbuf + row * 128
                                + (((hf * 4 + g) ^ (row & 7)) << 4));
        }
        #pragma unroll
        for (int fm = 0; fm < 4; ++fm) {
            const int row = wr * 64 + fm * 16 + l15;
            const bf16x8 a0 = *(const bf16x8*)((const char*)Abuf + row * 128
                                + (((g) ^ (row & 7)) << 4));
            const bf16x8 a1 = *(const bf16x8*)((const char*)Abuf + row * 128
                                + (((4 + g) ^ (row & 7)) << 4));
            #pragma unroll
            for (int fn = 0; fn < 4; ++fn) {
                acc[fm][fn] = __builtin_amdgcn_mfma_f32_16x16x32_bf16(a0, bfr[fn][0], acc[fm][fn], 0, 0, 0);
                acc[fm][fn] = __builtin_amdgcn_mfma_f32_16x16x32_bf16(a1, bfr[fn][1], acc[fm][fn], 0, 0, 0);
            }
        }
    }

    // epilogue: D[row=am0+wr*64+fm*16+g*4+r][col=bn0+wc*64+fn*16+l15]
    #pragma unroll
    for (int fm = 0; fm < 4; ++fm)
        #pragma unroll
        for (int fn = 0; fn < 4; ++fn)
            #pragma unroll
            for (int r = 0; r < 4; ++r) {
                const int ar = am0 + wr * 64 + fm * 16 + g * 4 + r;
                const int bc = bn0 + wc * 64 + fn * 16 + l15;
                if (MODE == 0) {
                    // ar = s, bc = o in [0,1024): q then k
                    const int which = bc >> 9, h = (bc >> 6) & 7, d = bc & 63;
                    ushort* O = (ushort*)outp;
                    O[(long)which * 4194304 + (((long)(bz * NHEAD + h)) * S_TOT + ar) * DIMH + d]
                        = f2bf(acc[fm][fn][r]);
                } else if (MODE == 1) {
                    // ar = o' in [0,512) (v rows), bc = s
                    const int h = ar >> 6, d = ar & 63;
                    ushort* O = (ushort*)outp;
                    O[(((long)(bz * NHEAD + h)) * DIMH + d) * S_TOT + bc] = f2bf(acc[fm][fn][r]);
                } else {
                    // ar = o in [0,256), bc = s
                    float* O = (float*)outp;
                    O[((long)bz * CIN + ar) * S_TOT + bc] = acc[fm][fn][r] + bias[ar];
                }
            }
}

// ---------------------------------------------------------------------------
// Flash attention, bf16 MFMA 16x16x32 (unchanged core; bf16 output epilogue).
// ---------------------------------------------------------------------------
__global__ __launch_bounds__(256)
void attn_mfma_kernel(const ushort* __restrict__ qg, const ushort* __restrict__ kg,
                      const ushort* __restrict__ vg, ushort* __restrict__ aout) {
    __shared__ __attribute__((aligned(16))) ushort kbuf[64 * 64];
    __shared__ __attribute__((aligned(16))) ushort vbuf[64 * 64];
    __shared__ __attribute__((aligned(16))) ushort pbuf[4][16 * 64];

    const int t = threadIdx.x;
    const int lane = t & 63, wid = t >> 6;
    const int l15 = lane & 15, g = lane >> 4;
    const int h = blockIdx.y, b = blockIdx.z;
    const int bh = b * NHEAD + h;
    const int qrow0 = blockIdx.x * 64 + wid * 16;

    const ushort* qp = qg + ((long)bh * S_TOT + qrow0 + l15) * DIMH + g * 8;
    const bf16x8 qf0 = *(const bf16x8*)qp;
    const bf16x8 qf1 = *(const bf16x8*)(qp + 32);

    f32x4 oacc[4];
    float mrun[4], lrun[4];
    #pragma unroll
    for (int r = 0; r < 4; ++r) { mrun[r] = -1e30f; lrun[r] = 0.f; }
    #pragma unroll
    for (int f = 0; f < 4; ++f) oacc[f] = (f32x4){0.f, 0.f, 0.f, 0.f};

    const long kg_base = (long)bh * S_TOT * DIMH;
    const long vg_base = (long)bh * DIMH * S_TOT;

    const int sl = lane & 7, sr = lane >> 3;
    const int swz = sl ^ sr;
    char* kdst = (char*)kbuf + wid * 1024;
    char* vdst = (char*)vbuf + wid * 1024;
    char* pbase = (char*)(&pbuf[wid][0]);

    for (int kt0 = 0; kt0 < S_TOT / 64; ++kt0) {
        const long key0 = (long)kt0 * 64;
        __syncthreads();
        #pragma unroll
        for (int c = 0; c < 2; ++c) {
            const int row = (wid + c * 4) * 8 + sr;
            const char* src = (const char*)(kg + kg_base + (key0 + row) * DIMH) + swz * 16;
            __builtin_amdgcn_global_load_lds((gv_t*)src, (lv_t*)(kdst + c * 4096), 16, 0, 0);
        }
        #pragma unroll
        for (int c = 0; c < 2; ++c) {
            const int d = (wid + c * 4) * 8 + sr;
            const char* src = (const char*)(vg + vg_base + (long)d * S_TOT + key0) + swz * 16;
            __builtin_amdgcn_global_load_lds((gv_t*)src, (lv_t*)(vdst + c * 4096), 16, 0, 0);
        }
        asm volatile("s_waitcnt vmcnt(0)" ::: "memory");
        __syncthreads();

        f32x4 sacc[4];
        #pragma unroll
        for (int kt = 0; kt < 4; ++kt) {
            sacc[kt] = (f32x4){0.f, 0.f, 0.f, 0.f};
            const int krow = kt * 16 + l15;
            const int ks = krow & 7;
            const bf16x8 kf0 = *(const bf16x8*)((const char*)kbuf + krow * 128 + ((g) ^ ks) * 16);
            sacc[kt] = __builtin_amdgcn_mfma_f32_16x16x32_bf16(qf0, kf0, sacc[kt], 0, 0, 0);
            const bf16x8 kf1 = *(const bf16x8*)((const char*)kbuf + krow * 128 + ((4 + g) ^ ks) * 16);
            sacc[kt] = __builtin_amdgcn_mfma_f32_16x16x32_bf16(qf1, kf1, sacc[kt], 0, 0, 0);
            #pragma unroll
            for (int r = 0; r < 4; ++r) sacc[kt][r] *= 0.125f;
        }

        float mx[4];
        #pragma unroll
        for (int r = 0; r < 4; ++r)
            mx[r] = fmaxf(fmaxf(sacc[0][r], sacc[1][r]), fmaxf(sacc[2][r], sacc[3][r]));
        #pragma unroll
        for (int off = 1; off < 16; off <<= 1) {
            #pragma unroll
            for (int r = 0; r < 4; ++r)
                mx[r] = fmaxf(mx[r], __shfl_xor(mx[r], off, 64));
        }
        float al[4];
        #pragma unroll
        for (int r = 0; r < 4; ++r) {
            const float mn = fmaxf(mrun[r], mx[r]);
            al[r] = __expf(mrun[r] - mn);
            mrun[r] = mn;
        }
        float ps[4] = {0.f, 0.f, 0.f, 0.f};
        #pragma unroll
        for (int kt = 0; kt < 4; ++kt) {
            #pragma unroll
            for (int r = 0; r < 4; ++r) {
                const float p = __expf(sacc[kt][r] - mrun[r]);
                ps[r] += p;
                const int q = g * 4 + r;
                *(ushort*)(pbase + q * 128 + (((kt * 2 + (l15 >> 3)) ^ (q & 7)) << 4)
                           + (l15 & 7) * 2) = f2bf(p);
            }
        }
        #pragma unroll
        for (int off = 1; off < 16; off <<= 1) {
            #pragma unroll
            for (int r = 0; r < 4; ++r)
                ps[r] += __shfl_xor(ps[r], off, 64);
        }
        #pragma unroll
        for (int r = 0; r < 4; ++r)
            lrun[r] = lrun[r] * al[r] + ps[r];
        #pragma unroll
        for (int f = 0; f < 4; ++f)
            #pragma unroll
            for (int r = 0; r < 4; ++r)
                oacc[f][r] *= al[r];

        #pragma unroll
        for (int ks = 0; ks < 2; ++ks) {
            const bf16x8 pf = *(const bf16x8*)(pbase + l15 * 128
                                + (((ks * 4 + g) ^ (l15 & 7)) << 4));
            #pragma unroll
            for (int f = 0; f < 4; ++f) {
                const int vrow = f * 16 + l15;
                const bf16x8 vf = *(const bf16x8*)((const char*)vbuf + vrow * 128
                                    + (((ks * 4 + g) ^ (vrow & 7)) << 4));
                oacc[f] = __builtin_amdgcn_mfma_f32_16x16x32_bf16(pf, vf, oacc[f], 0, 0, 0);
            }
        }
    }

    float inv[4];
    #pragma unroll
    for (int r = 0; r < 4; ++r) inv[r] = 1.0f / lrun[r];
    #pragma unroll
    for (int f = 0; f < 4; ++f)
        #pragma unroll
        for (int r = 0; r < 4; ++r) {
            const long srow = (long)b * S_TOT + qrow0 + g * 4 + r;
            aout[srow * HID + h * 64 + f * 16 + l15] = f2bf(oacc[f][r] * inv[r]);
        }
}

// ---------------------------------------------------------------------------
extern "C" void kernel_launch(void* const* d_in, const int* in_sizes, int n_in,
                              void* d_out, int out_size, void* d_ws, size_t ws_size,
                              hipStream_t stream) {
    const float* x     = (const float*)d_in[0];
    const float* w_qkv = (const float*)d_in[1];
    const float* w_out = (const float*)d_in[2];
    const float* b_out = (const float*)d_in[3];
    float* out = (float*)d_out;

    const long PERQKV = (long)2 * NHEAD * S_TOT * DIMH;   // 4,194,304 elems
    ushort* qws = (ushort*)d_ws;
    ushort* kws = qws + PERQKV;
    ushort* vws = kws + PERQKV;
    ushort* xt  = vws + PERQKV;                           // [2][4096][256]
    ushort* wqb = xt + (long)2 * S_TOT * CIN;             // [1536][256]
    ushort* wob = wqb + (long)3 * HID * CIN;              // [256][512]
    ushort* awb = wob + (long)CIN * HID;                  // [2][4096][512]

    cast_f32_bf16<<<dim3((3 * HID * CIN / 4 + 255) / 256), 256, 0, stream>>>(
        w_qkv, wqb, (long)3 * HID * CIN);
    cast_f32_bf16<<<dim3((CIN * HID / 4 + 255) / 256), 256, 0, stream>>>(
        w_out, wob, (long)CIN * HID);
    transpose_cast_x<<<dim3(S_TOT / 64, CIN / 64, 2), 256, 0, stream>>>(x, xt);

    // QK: D[s][o], A=xt (batch-strided), B=w_qkv rows 0..1023 (shared)
    gemm_mfma_kernel<0><<<dim3(1024 / 128, S_TOT / 128, 2), 256, 0, stream>>>(
        xt, wqb, qws, nullptr, CIN, (long)S_TOT * CIN, 0L);
    // V: D[o'][s], A=w_qkv rows 1024..1535 (shared), B=xt (batch-strided)
    gemm_mfma_kernel<1><<<dim3(S_TOT / 128, 512 / 128, 2), 256, 0, stream>>>(
        wqb + (long)1024 * CIN, xt, vws, nullptr, CIN, 0L, (long)S_TOT * CIN);

    attn_mfma_kernel<<<dim3(S_TOT / 64, NHEAD, 2), 256, 0, stream>>>(qws, kws, vws, awb);

    // out-proj: D[o][s] fp32 + bias, A=w_out (shared), B=attn bf16 (strided)
    gemm_mfma_kernel<2><<<dim3(S_TOT / 128, CIN / 128, 2), 256, 0, stream>>>(
        wob, awb, out, b_out, HID, 0L, (long)S_TOT * HID);
}

// Round 4
// 167.993 us; speedup vs baseline: 64.8272x; 1.5559x over previous
//
#include <hip/hip_runtime.h>
#include <cmath>

#define S_TOT 4096
#define CIN   256
#define HID   512
#define NHEAD 8
#define DIMH  64

typedef __attribute__((ext_vector_type(8))) short bf16x8;
typedef __attribute__((ext_vector_type(4))) float f32x4;
typedef __attribute__((address_space(1))) const void gv_t;
typedef __attribute__((address_space(3))) void lv_t;

__device__ __forceinline__ ushort f2bf(float f) {
    union { float f; unsigned u; } v; v.f = f;
    unsigned r = (v.u + 0x7FFFu + ((v.u >> 16) & 1u)) >> 16;
    return (ushort)r;
}

__device__ __forceinline__ float exp2_fast(float x) {
    float r; asm("v_exp_f32 %0, %1" : "=v"(r) : "v"(x)); return r;
}

__device__ __forceinline__ unsigned cvt_pk_bf16(float lo, float hi) {
    unsigned r; asm("v_cvt_pk_bf16_f32 %0, %1, %2" : "=v"(r) : "v"(lo), "v"(hi)); return r;
}

// 0.125 (1/sqrt(64)) * log2(e): folds softmax base-2 conversion into Q.
#define QSCALE 0.18033688011112042f

// ---------------------------------------------------------------------------
// Elementwise fp32 -> bf16 cast (vectorized), n % 4 == 0
// ---------------------------------------------------------------------------
__global__ __launch_bounds__(256)
void cast_f32_bf16(const float* __restrict__ in, ushort* __restrict__ out, long n) {
    long i = ((long)blockIdx.x * 256 + threadIdx.x) * 4;
    if (i < n) {
        float4 v = *(const float4*)&in[i];
        ushort4 p;
        p.x = f2bf(v.x); p.y = f2bf(v.y); p.z = f2bf(v.z); p.w = f2bf(v.w);
        *(ushort4*)&out[i] = p;
    }
}

// ---------------------------------------------------------------------------
// Transpose-cast: x [b][256][4096] fp32 -> xt [b][4096][256] bf16
// ---------------------------------------------------------------------------
__global__ __launch_bounds__(256)
void transpose_cast_x(const float* __restrict__ x, ushort* __restrict__ xt) {
    __shared__ float tb[64][65];
    const int t = threadIdx.x;
    const int s0 = blockIdx.x * 64, c0 = blockIdx.y * 64;
    const long xb = (long)blockIdx.z * CIN * S_TOT;
    #pragma unroll
    for (int i = 0; i < 16; ++i) {
        int idx = t + i * 256;
        int c = idx >> 6, s = idx & 63;
        tb[c][s] = x[xb + (long)(c0 + c) * S_TOT + s0 + s];
    }
    __syncthreads();
    const long ob = (long)blockIdx.z * S_TOT * CIN;
    const int s = t >> 2, cq = (t & 3) * 16;
    #pragma unroll
    for (int j = 0; j < 4; ++j) {
        ushort4 pk;
        pk.x = f2bf(tb[cq + j * 4 + 0][s]);
        pk.y = f2bf(tb[cq + j * 4 + 1][s]);
        pk.z = f2bf(tb[cq + j * 4 + 2][s]);
        pk.w = f2bf(tb[cq + j * 4 + 3][s]);
        *(ushort4*)&xt[ob + (long)(s0 + s) * CIN + c0 + cq + j * 4] = pk;
    }
}

// ---------------------------------------------------------------------------
// bf16 MFMA GEMM: D[ar][br] = sum_k A[ar][k] * B[br][k]   (both K-contiguous)
// MODE 0: A=xt, B=w_qkv[0:1024] -> q (pre-scaled by QSCALE) / k, [bh][s][64]
// MODE 1: A=w_qkv[1024:1536], B=xt -> v [bh][d][s]
// MODE 2: A=w_out, B=attn-bf16 -> out [b][o][s] fp32 + bias
// ---------------------------------------------------------------------------
template<int MODE>
__global__ __launch_bounds__(256)
void gemm_mfma_kernel(const ushort* __restrict__ Ag, const ushort* __restrict__ Bg,
                      void* __restrict__ outp, const float* __restrict__ bias,
                      int Kdim, long strideA, long strideB) {
    __shared__ __attribute__((aligned(16))) ushort Abuf[128 * 64];
    __shared__ __attribute__((aligned(16))) ushort Bbuf[128 * 64];
    const int t = threadIdx.x, lane = t & 63;
    const int l15 = lane & 15, g = lane >> 4;
    const int wid = t >> 6, wr = wid >> 1, wc = wid & 1;
    const int bz = blockIdx.z;
    const int am0 = blockIdx.y * 128, bn0 = blockIdx.x * 128;
    Ag += (long)bz * strideA;
    Bg += (long)bz * strideB;

    f32x4 acc[4][4];
    #pragma unroll
    for (int i = 0; i < 4; ++i)
        #pragma unroll
        for (int j = 0; j < 4; ++j)
            acc[i][j] = (f32x4){0.f, 0.f, 0.f, 0.f};

    for (int k0 = 0; k0 < Kdim; k0 += 64) {
        __syncthreads();
        #pragma unroll
        for (int i = 0; i < 4; ++i) {
            const int chunk = t + i * 256;
            const int row = chunk >> 3, sl = chunk & 7;
            const ushort* srcA = Ag + (long)(am0 + row) * Kdim + k0 + ((sl ^ (row & 7)) << 3);
            __builtin_amdgcn_global_load_lds((gv_t*)srcA,
                (lv_t*)((char*)Abuf + (i * 256 + (t & ~63)) * 16), 16, 0, 0);
            const ushort* srcB = Bg + (long)(bn0 + row) * Kdim + k0 + ((sl ^ (row & 7)) << 3);
            __builtin_amdgcn_global_load_lds((gv_t*)srcB,
                (lv_t*)((char*)Bbuf + (i * 256 + (t & ~63)) * 16), 16, 0, 0);
        }
        asm volatile("s_waitcnt vmcnt(0)" ::: "memory");
        __syncthreads();

        bf16x8 bfr[4][2];
        #pragma unroll
        for (int fn = 0; fn < 4; ++fn) {
            const int row = wc * 64 + fn * 16 + l15;
            #pragma unroll
            for (int hf = 0; hf < 2; ++hf)
                bfr[fn][hf] = *(const bf16x8*)((const char*)Bbuf + row * 128
                                + (((hf * 4 + g) ^ (row & 7)) << 4));
        }
        #pragma unroll
        for (int fm = 0; fm < 4; ++fm) {
            const int row = wr * 64 + fm * 16 + l15;
            const bf16x8 a0 = *(const bf16x8*)((const char*)Abuf + row * 128
                                + (((g) ^ (row & 7)) << 4));
            const bf16x8 a1 = *(const bf16x8*)((const char*)Abuf + row * 128
                                + (((4 + g) ^ (row & 7)) << 4));
            #pragma unroll
            for (int fn = 0; fn < 4; ++fn) {
                acc[fm][fn] = __builtin_amdgcn_mfma_f32_16x16x32_bf16(a0, bfr[fn][0], acc[fm][fn], 0, 0, 0);
                acc[fm][fn] = __builtin_amdgcn_mfma_f32_16x16x32_bf16(a1, bfr[fn][1], acc[fm][fn], 0, 0, 0);
            }
        }
    }

    #pragma unroll
    for (int fm = 0; fm < 4; ++fm)
        #pragma unroll
        for (int fn = 0; fn < 4; ++fn)
            #pragma unroll
            for (int r = 0; r < 4; ++r) {
                const int ar = am0 + wr * 64 + fm * 16 + g * 4 + r;
                const int bc = bn0 + wc * 64 + fn * 16 + l15;
                if (MODE == 0) {
                    const int which = bc >> 9, h = (bc >> 6) & 7, d = bc & 63;
                    const float scl = (which == 0) ? QSCALE : 1.0f;
                    ushort* O = (ushort*)outp;
                    O[(long)which * 4194304 + (((long)(bz * NHEAD + h)) * S_TOT + ar) * DIMH + d]
                        = f2bf(acc[fm][fn][r] * scl);
                } else if (MODE == 1) {
                    const int h = ar >> 6, d = ar & 63;
                    ushort* O = (ushort*)outp;
                    O[(((long)(bz * NHEAD + h)) * DIMH + d) * S_TOT + bc] = f2bf(acc[fm][fn][r]);
                } else {
                    float* O = (float*)outp;
                    O[((long)bz * CIN + ar) * S_TOT + bc] = acc[fm][fn][r] + bias[ar];
                }
            }
}

// ---------------------------------------------------------------------------
// Flash attention, swapped-QK (mfma(K,Q) -> S^T), in-register softmax:
// lane owns all 64 scores of q = lane&15 (16 regs + 2 shuffles for reduce).
// Q pre-scaled by 0.125*log2e -> exp is bare v_exp_f32. Defer-max THR=8.
// P packed with v_cvt_pk_bf16_f32, 4x ds_write_b64 (swizzled). K/V LDS
// double-buffered: stage t+1 issued before compute of t, one barrier/tile.
// ---------------------------------------------------------------------------
__global__ __launch_bounds__(256)
void attn_mfma_kernel(const ushort* __restrict__ qg, const ushort* __restrict__ kg,
                      const ushort* __restrict__ vg, ushort* __restrict__ aout) {
    __shared__ __attribute__((aligned(16))) ushort kbuf[2][64 * 64];
    __shared__ __attribute__((aligned(16))) ushort vbuf[2][64 * 64];
    __shared__ __attribute__((aligned(16))) ushort pbuf[4][16 * 64];

    const int t = threadIdx.x;
    const int lane = t & 63, wid = t >> 6;
    const int l15 = lane & 15, g = lane >> 4;
    const int h = blockIdx.y, b = blockIdx.z;
    const int bh = b * NHEAD + h;
    const int qrow0 = blockIdx.x * 64 + wid * 16;

    // Q B-fragment: row = q = l15, k-slot g (already scaled by QSCALE)
    const ushort* qp = qg + ((long)bh * S_TOT + qrow0 + l15) * DIMH + g * 8;
    const bf16x8 qf0 = *(const bf16x8*)qp;
    const bf16x8 qf1 = *(const bf16x8*)(qp + 32);

    f32x4 oacc[4];
    #pragma unroll
    for (int f = 0; f < 4; ++f) oacc[f] = (f32x4){0.f, 0.f, 0.f, 0.f};
    float mrun = -3e38f, lrun = 0.f;   // q = l15 domain

    const long kg_base = (long)bh * S_TOT * DIMH;
    const long vg_base = (long)bh * DIMH * S_TOT;
    const int sl = lane & 7, sr = lane >> 3;
    const int swz = sl ^ sr;
    char* pbase = (char*)(&pbuf[wid][0]);

    auto STAGE = [&](int buf, long key0) {
        char* kdst = (char*)(&kbuf[buf][0]) + wid * 1024;
        char* vdst = (char*)(&vbuf[buf][0]) + wid * 1024;
        #pragma unroll
        for (int c = 0; c < 2; ++c) {
            const int row = (wid + c * 4) * 8 + sr;
            const char* srcK = (const char*)(kg + kg_base + (key0 + row) * DIMH) + swz * 16;
            __builtin_amdgcn_global_load_lds((gv_t*)srcK, (lv_t*)(kdst + c * 4096), 16, 0, 0);
            const char* srcV = (const char*)(vg + vg_base + (long)row * S_TOT + key0) + swz * 16;
            __builtin_amdgcn_global_load_lds((gv_t*)srcV, (lv_t*)(vdst + c * 4096), 16, 0, 0);
        }
    };

    STAGE(0, 0);
    asm volatile("s_waitcnt vmcnt(0)" ::: "memory");
    __syncthreads();

    for (int kt0 = 0; kt0 < S_TOT / 64; ++kt0) {
        const int cur = kt0 & 1;
        if (kt0 + 1 < S_TOT / 64) STAGE(cur ^ 1, (long)(kt0 + 1) * 64);

        const char* kb_ = (const char*)(&kbuf[cur][0]);
        const char* vb_ = (const char*)(&vbuf[cur][0]);

        // --- S^T = K Q^T (lane: q=l15, key = kb*16 + g*4 + r) ---
        f32x4 sacc[4];
        __builtin_amdgcn_s_setprio(1);
        #pragma unroll
        for (int kb = 0; kb < 4; ++kb) {
            const int krow = kb * 16 + l15, ks = krow & 7;
            const bf16x8 kf0 = *(const bf16x8*)(kb_ + krow * 128 + ((g ^ ks) << 4));
            const bf16x8 kf1 = *(const bf16x8*)(kb_ + krow * 128 + (((4 + g) ^ ks) << 4));
            sacc[kb] = (f32x4){0.f, 0.f, 0.f, 0.f};
            sacc[kb] = __builtin_amdgcn_mfma_f32_16x16x32_bf16(kf0, qf0, sacc[kb], 0, 0, 0);
            sacc[kb] = __builtin_amdgcn_mfma_f32_16x16x32_bf16(kf1, qf1, sacc[kb], 0, 0, 0);
        }
        __builtin_amdgcn_s_setprio(0);

        // --- in-register softmax ---
        float tmax = fmaxf(fmaxf(sacc[0][0], sacc[0][1]), fmaxf(sacc[0][2], sacc[0][3]));
        #pragma unroll
        for (int kb = 1; kb < 4; ++kb)
            tmax = fmaxf(tmax, fmaxf(fmaxf(sacc[kb][0], sacc[kb][1]),
                                     fmaxf(sacc[kb][2], sacc[kb][3])));
        tmax = fmaxf(tmax, __shfl_xor(tmax, 16, 64));
        tmax = fmaxf(tmax, __shfl_xor(tmax, 32, 64));

        if (__any(tmax > mrun + 8.0f)) {       // defer-max (T13)
            const float mn = fmaxf(mrun, tmax);
            const float al = exp2_fast(mrun - mn);
            lrun *= al;
            #pragma unroll
            for (int r = 0; r < 4; ++r) {
                const float alg = __shfl(al, g * 4 + r, 64);
                #pragma unroll
                for (int f = 0; f < 4; ++f) oacc[f][r] *= alg;
            }
            mrun = mn;
        }

        float psum = 0.f;
        #pragma unroll
        for (int kb = 0; kb < 4; ++kb) {
            const float p0 = exp2_fast(sacc[kb][0] - mrun);
            const float p1 = exp2_fast(sacc[kb][1] - mrun);
            const float p2 = exp2_fast(sacc[kb][2] - mrun);
            const float p3 = exp2_fast(sacc[kb][3] - mrun);
            psum += (p0 + p1) + (p2 + p3);
            const unsigned d0 = cvt_pk_bf16(p0, p1);
            const unsigned d1 = cvt_pk_bf16(p2, p3);
            // keys 16*kb + 4*g + 0..3 of row q=l15; 16B-slot = 2kb+(g>>1), swz by q&7
            *(unsigned long long*)(pbase + l15 * 128
                + ((((kb << 1) + (g >> 1)) ^ (l15 & 7)) << 4) + ((g & 1) << 3))
                = ((unsigned long long)d1 << 32) | (unsigned long long)d0;
        }
        psum += __shfl_xor(psum, 16, 64);
        psum += __shfl_xor(psum, 32, 64);
        lrun += psum;

        // --- O += P V ---
        __builtin_amdgcn_s_setprio(1);
        #pragma unroll
        for (int ks = 0; ks < 2; ++ks) {
            const bf16x8 pf = *(const bf16x8*)(pbase + l15 * 128
                                + (((ks * 4 + g) ^ (l15 & 7)) << 4));
            #pragma unroll
            for (int f = 0; f < 4; ++f) {
                const int vrow = f * 16 + l15;
                const bf16x8 vf = *(const bf16x8*)(vb_ + vrow * 128
                                    + (((ks * 4 + g) ^ (vrow & 7)) << 4));
                oacc[f] = __builtin_amdgcn_mfma_f32_16x16x32_bf16(pf, vf, oacc[f], 0, 0, 0);
            }
        }
        __builtin_amdgcn_s_setprio(0);

        asm volatile("s_waitcnt vmcnt(0)" ::: "memory");
        __syncthreads();
    }

    // epilogue: q = g*4+r rows; lrun transposed from l15 domain via shfl
    #pragma unroll
    for (int r = 0; r < 4; ++r) {
        const float inv = 1.0f / __shfl(lrun, g * 4 + r, 64);
        const long srow = (long)b * S_TOT + qrow0 + g * 4 + r;
        #pragma unroll
        for (int f = 0; f < 4; ++f)
            aout[srow * HID + h * 64 + f * 16 + l15] = f2bf(oacc[f][r] * inv);
    }
}

// ---------------------------------------------------------------------------
extern "C" void kernel_launch(void* const* d_in, const int* in_sizes, int n_in,
                              void* d_out, int out_size, void* d_ws, size_t ws_size,
                              hipStream_t stream) {
    const float* x     = (const float*)d_in[0];
    const float* w_qkv = (const float*)d_in[1];
    const float* w_out = (const float*)d_in[2];
    const float* b_out = (const float*)d_in[3];
    float* out = (float*)d_out;

    const long PERQKV = (long)2 * NHEAD * S_TOT * DIMH;
    ushort* qws = (ushort*)d_ws;
    ushort* kws = qws + PERQKV;
    ushort* vws = kws + PERQKV;
    ushort* xt  = vws + PERQKV;
    ushort* wqb = xt + (long)2 * S_TOT * CIN;
    ushort* wob = wqb + (long)3 * HID * CIN;
    ushort* awb = wob + (long)CIN * HID;

    cast_f32_bf16<<<dim3((3 * HID * CIN / 4 + 255) / 256), 256, 0, stream>>>(
        w_qkv, wqb, (long)3 * HID * CIN);
    cast_f32_bf16<<<dim3((CIN * HID / 4 + 255) / 256), 256, 0, stream>>>(
        w_out, wob, (long)CIN * HID);
    transpose_cast_x<<<dim3(S_TOT / 64, CIN / 64, 2), 256, 0, stream>>>(x, xt);

    gemm_mfma_kernel<0><<<dim3(1024 / 128, S_TOT / 128, 2), 256, 0, stream>>>(
        xt, wqb, qws, nullptr, CIN, (long)S_TOT * CIN, 0L);
    gemm_mfma_kernel<1><<<dim3(S_TOT / 128, 512 / 128, 2), 256, 0, stream>>>(
        wqb + (long)1024 * CIN, xt, vws, nullptr, CIN, 0L, (long)S_TOT * CIN);

    attn_mfma_kernel<<<dim3(S_TOT / 64, NHEAD, 2), 256, 0, stream>>>(qws, kws, vws, awb);

    gemm_mfma_kernel<2><<<dim3(S_TOT / 128, CIN / 128, 2), 256, 0, stream>>>(
        wob, awb, out, b_out, HID, 0L, (long)S_TOT * HID);
}